// Round 16
// baseline (214.225 us; speedup 1.0000x reference)
//
#include <hip/hip_runtime.h>

#define NN 8
#define CC 19
#define HH 512
#define WW 512
#define HW (HH*WW)            // 262144
#define NPIX (NN*HW)          // 2097152
#define NPLANE (NN*CC)        // 152
#define BIGV (1<<20)
#define M7 0x7F7F7F7Fu

// persistent scratch in device globals (zero-initialized at module load;
// the last wscan block restores the zero-state -> replay-invariant)
__device__ unsigned char g_tT[NPIX];                  // targets transposed [n][w][h]
__device__ unsigned char g_pred[NPIX];                // row-major [n][h][w]
__device__ float g_lse[NPIX];                         // row-major
__device__ unsigned char g_inter[(size_t)NPLANE*HW];  // blocked [plane][wt:8][h:512][wl:64]
__device__ float g_ce;
__device__ float g_part[64][16];                      // padded border partials
__device__ unsigned int g_present_mask;
__device__ unsigned int g_done;                       // wscan completion counter

// bytewise x==0 -> 0x80 flag (exact, no cross-byte carry)
__device__ __forceinline__ unsigned int eqz(unsigned int x) {
  unsigned int y = (x & M7) + M7;
  return ~(y | x | M7);
}

// per-pixel softmax stats, 8 px/thread, channel-major (R13-verbatim)
__global__ __launch_bounds__(256) void k_pixel(const float* __restrict__ slices,
                                               const int* __restrict__ targets) {
  int bp = blockIdx.x * 2048;                   // block tile: 2048 consecutive px
  int n = bp >> 18;                             // HW = 2^18, 128 blocks/image
  int r = bp & (HW - 1);
  int wv = threadIdx.x >> 6;
  int lane = threadIdx.x & 63;
  int o0 = wv * 512 + lane * 4;
  int o1 = o0 + 256;
  const float* base = slices + (size_t)n * CC * HW + r;

  const int4* t4p = (const int4*)(targets + bp);
  int4 ta = t4p[o0 >> 2];
  int4 tb = t4p[o1 >> 2];
  int t[8] = {ta.x, ta.y, ta.z, ta.w, tb.x, tb.y, tb.z, tb.w};

  float m[8], s[8], pk[8];
  int a[8];
  {
    float4 x0 = *(const float4*)(base + o0);
    float4 x1 = *(const float4*)(base + o1);
    float x[8] = {x0.x, x0.y, x0.z, x0.w, x1.x, x1.y, x1.z, x1.w};
#pragma unroll
    for (int j = 0; j < 8; ++j) {
      m[j] = x[j];
      a[j] = 0;
      s[j] = __expf(x[j]);
      pk[j] = (t[j] == 0) ? x[j] : 0.f;
    }
  }
#pragma unroll 2
  for (int c = 1; c < CC; ++c) {
    float4 x0 = *(const float4*)(base + (size_t)c * HW + o0);
    float4 x1 = *(const float4*)(base + (size_t)c * HW + o1);
    float x[8] = {x0.x, x0.y, x0.z, x0.w, x1.x, x1.y, x1.z, x1.w};
#pragma unroll
    for (int j = 0; j < 8; ++j) {
      if (x[j] > m[j]) { m[j] = x[j]; a[j] = c; }
      s[j] += __expf(x[j]);
      pk[j] = (c == t[j]) ? x[j] : pk[j];
    }
  }

  float l[8];
  float ce_local = 0.f;
  unsigned int msk = 0u;
#pragma unroll
  for (int j = 0; j < 8; ++j) {
    l[j] = __logf(s[j]);
    if (t[j] != 255) ce_local += l[j] - pk[j];
    if ((unsigned)t[j] < CC) msk |= 1u << t[j];
  }

  ((float4*)(g_lse + bp))[o0 >> 2] = make_float4(l[0], l[1], l[2], l[3]);
  ((float4*)(g_lse + bp))[o1 >> 2] = make_float4(l[4], l[5], l[6], l[7]);
  ((uchar4*)(g_pred + bp))[o0 >> 2] =
      make_uchar4((unsigned char)a[0], (unsigned char)a[1],
                  (unsigned char)a[2], (unsigned char)a[3]);
  ((uchar4*)(g_pred + bp))[o1 >> 2] =
      make_uchar4((unsigned char)a[4], (unsigned char)a[5],
                  (unsigned char)a[6], (unsigned char)a[7]);
#pragma unroll
  for (int j = 0; j < 8; ++j) {
    int p = bp + ((j < 4) ? (o0 + j) : (o1 + j - 4));
    int h = (p >> 9) & 511;
    int w = p & 511;
    g_tT[((size_t)n << 18) + (size_t)w * HH + h] = (unsigned char)t[j];
  }

  __shared__ float sred[256];
  __shared__ unsigned int smsk[256];
  sred[threadIdx.x] = ce_local;
  smsk[threadIdx.x] = msk;
  __syncthreads();
  for (int st = 128; st > 0; st >>= 1) {
    if (threadIdx.x < st) {
      sred[threadIdx.x] += sred[threadIdx.x + st];
      smsk[threadIdx.x] |= smsk[threadIdx.x + st];
    }
    __syncthreads();
  }
  if (threadIdx.x == 0) {
    atomicAdd(&g_ce, sred[0]);
    atomicOr(&g_present_mask, smsk[0]);
  }
}

// H-axis scan (R7-verbatim)
__global__ __launch_bounds__(512, 4) void k_hscan() {
  int plane = blockIdx.x >> 3;          // 152 planes
  int wt = blockIdx.x & 7;
  int hc = threadIdx.x >> 6;            // 8 h-chunks of 64
  int wl = threadIdx.x & 63;
  int c = plane % CC;
  int n = plane / CC;
  int w = wt * 64 + wl;
  const unsigned char* colC = g_tT + ((size_t)n << 18) + (size_t)w * HH + hc * 64;

  uint4 ca = *(const uint4*)(colC);
  uint4 cb = *(const uint4*)(colC + 16);
  uint4 cc2 = *(const uint4*)(colC + 32);
  uint4 cd = *(const uint4*)(colC + 48);
  unsigned int cw[16];
  cw[0]=ca.x; cw[1]=ca.y; cw[2]=ca.z; cw[3]=ca.w;
  cw[4]=cb.x; cw[5]=cb.y; cw[6]=cb.z; cw[7]=cb.w;
  cw[8]=cc2.x; cw[9]=cc2.y; cw[10]=cc2.z; cw[11]=cc2.w;
  cw[12]=cd.x; cw[13]=cd.y; cw[14]=cd.z; cw[15]=cd.w;

  unsigned int lw[16];
#pragma unroll
  for (int i = 0; i < 16; ++i) lw[i] = __shfl_up(cw[i], 1, 64);
  if (wl == 0) {
    if (w > 0) {
      const unsigned char* colL = colC - HH;
      uint4 la = *(const uint4*)(colL);
      uint4 lb = *(const uint4*)(colL + 16);
      uint4 lc = *(const uint4*)(colL + 32);
      uint4 ld = *(const uint4*)(colL + 48);
      lw[0]=la.x; lw[1]=la.y; lw[2]=la.z; lw[3]=la.w;
      lw[4]=lb.x; lw[5]=lb.y; lw[6]=lb.z; lw[7]=lb.w;
      lw[8]=lc.x; lw[9]=lc.y; lw[10]=lc.z; lw[11]=lc.w;
      lw[12]=ld.x; lw[13]=ld.y; lw[14]=ld.z; lw[15]=ld.w;
    } else {
#pragma unroll
      for (int i = 0; i < 16; ++i) lw[i] = cw[i];
    }
  }

  __shared__ unsigned char s_edge[8][64];
  s_edge[hc][wl] = (unsigned char)(cw[0] & 255u);
  __syncthreads();
  unsigned int tnl = (hc < 7) ? (unsigned int)s_edge[hc + 1][wl]
                              : ((cw[15] >> 24) & 255u);

  unsigned int bc = (unsigned int)c * 0x01010101u;
  int v[64];
  int prev = BIGV;
#pragma unroll
  for (int i = 0; i < 16; ++i) {
    unsigned int cwi = cw[i];
    unsigned int nxt = (i < 15) ? (cw[i + 1] & 255u) : tnl;
    unsigned int tnw = (cwi >> 8) | (nxt << 24);
    unsigned int zc = eqz(cwi ^ bc);
    unsigned int zn = eqz(tnw ^ bc);
    unsigned int zl = eqz(lw[i] ^ bc);
    unsigned int bb = (zc ^ zn) | (zc ^ zl);
#pragma unroll
    for (int k = 0; k < 4; ++k) {
      int bit = (int)((bb >> (8 * k + 7)) & 1u);
      prev = min(bit ? 0 : 255, prev + 1);
      v[4 * i + k] = prev;
    }
  }

  __shared__ int s_car[8][64];
  s_car[hc][wl] = v[63];
  __syncthreads();
  int F = BIGV;
#pragma unroll
  for (int i = 0; i < 7; ++i)
    if (i < hc) F = min(s_car[i][wl] + 1, F + 64);
#pragma unroll
  for (int k = 0; k < 64; ++k) v[k] = min(v[k], F + k);

#pragma unroll
  for (int k = 62; k >= 0; --k) v[k] = min(v[k], v[k + 1] + 1);

  __syncthreads();
  s_car[hc][wl] = v[0];
  __syncthreads();
  int B = BIGV;
#pragma unroll
  for (int j = 7; j >= 1; --j)
    if (j > hc) B = min(s_car[j][wl] + 1, B + 64);

  unsigned char* outb = g_inter + (((size_t)plane * 8 + wt) * HH + hc * 64) * 64 + wl;
#pragma unroll
  for (int k = 0; k < 64; ++k) {
    int outv = min(v[k], B + (63 - k));
    outb[(size_t)k * 64] = (unsigned char)outv;
  }
}

// W-axis scan, spill-proof: thread owns a 32-px segment (pw[8]+v[32] ~ 60
// VGPR, fits registers). Block = 256 thr = 16 rows x 16 segments; LDS carry
// exchange (verified algebra, SEGLEN=32); fused sparse accumulation.
// Last block finalizes.
__global__ __launch_bounds__(256, 4) void k_wscan(const float* __restrict__ slices,
                                                  float* __restrict__ out) {
  int plane = blockIdx.x >> 5;          // 152 planes
  int rg = blockIdx.x & 31;             // 32 row-groups of 16 rows
  int r = threadIdx.x >> 4;             // row within group [0,16)
  int s = threadIdx.x & 15;             // 32-px segment along w [0,16)
  int c = plane % CC;
  int n = plane / CC;
  int h = rg * 16 + r;
  size_t pibase = (size_t)plane * HW;

  // contiguous 32B: g_inter[plane][wt=s>>1][h][(s&1)*32 ..]
  const unsigned char* src =
      g_inter + pibase + (size_t)(s >> 1) * 32768 + (size_t)h * 64 + (s & 1) * 32;
  uint4 q0 = *(const uint4*)(src);
  uint4 q1 = *(const uint4*)(src + 16);
  unsigned int pw[8];
  pw[0]=q0.x; pw[1]=q0.y; pw[2]=q0.z; pw[3]=q0.w;
  pw[4]=q1.x; pw[5]=q1.y; pw[6]=q1.z; pw[7]=q1.w;

  // fused unpack + local forward min-plus scan
  int v[32];
  int prev = BIGV;
#pragma unroll
  for (int i = 0; i < 8; ++i) {
    unsigned int wd = pw[i];
#pragma unroll
    for (int k = 0; k < 4; ++k) {
      int b = (int)((wd >> (8 * k)) & 255u);
      prev = min(b, prev + 1);
      v[4 * i + k] = prev;
    }
  }

  __shared__ int s_car[16][17];
  s_car[r][s] = v[31];
  __syncthreads();
  // forward cross-segment carry: F(i+1) = min(f_last(i)+1, F(i)+32)
  int F = BIGV;
#pragma unroll
  for (int i = 0; i < 15; ++i)
    if (i < s) F = min(s_car[r][i] + 1, F + 32);
#pragma unroll
  for (int k = 0; k < 32; ++k) v[k] = min(v[k], F + k);

  // local backward scan
#pragma unroll
  for (int k = 30; k >= 0; --k) v[k] = min(v[k], v[k + 1] + 1);

  __syncthreads();
  s_car[r][s] = v[0];
  __syncthreads();
  int B = BIGV;
#pragma unroll
  for (int j = 15; j >= 1; --j)
    if (j > s) B = min(s_car[r][j] + 1, B + 32);

  // fused sparse accumulation
  float pres = ((g_present_mask >> c) & 1u) ? 1.f : 0.f;
  float acc = 0.f;
#pragma unroll
  for (int k = 0; k < 32; ++k) {
    int D = min(v[k], B + (31 - k));
    int d = D - 5;                        // BORDER_DILATE
    if (d > 0) {
      int w = s * 32 + k;
      int pix = (n * HH + h) * WW + w;
      int pcv = g_pred[pix];
      int pnv = (h + 1 < HH) ? g_pred[pix + WW] : pcv;
      int plv = (w > 0) ? g_pred[pix - 1] : pcv;
      bool ec = (pcv == c);
      if ((ec != (pnv == c)) || (ec != (plv == c))) {
        float x = slices[((size_t)n * CC + c) * HW + (size_t)h * WW + w];
        float smv = __expf(x - g_lse[pix]);
        acc += smv * (float)d;
      }
    }
  }

  // block reduce (LDS) + one atomic per block
  __shared__ float sred[256];
  sred[threadIdx.x] = acc;
  __syncthreads();
  for (int st = 128; st > 0; st >>= 1) {
    if (threadIdx.x < st) sred[threadIdx.x] += sred[threadIdx.x + st];
    __syncthreads();
  }
  if (threadIdx.x == 0) atomicAdd(&g_part[blockIdx.x & 63][0], sred[0] * pres);

  // last-block finalize (no separate k_final launch)
  __shared__ int s_last;
  __syncthreads();
  if (threadIdx.x == 0) {
    __threadfence();
    unsigned int old = atomicAdd(&g_done, 1u);
    s_last = (old == (unsigned int)(gridDim.x - 1)) ? 1 : 0;
  }
  __syncthreads();
  if (s_last && threadIdx.x < 64) {
    __threadfence();
    float b = atomicAdd(&g_part[threadIdx.x][0], 0.f);   // coherent read
#pragma unroll
    for (int o = 32; o > 0; o >>= 1) b += __shfl_down(b, o, 64);
    if (threadIdx.x == 0) {
      out[0] = g_ce + sqrtf(b);           // BORDER_WEIGHT=1, power=0.5
      g_ce = 0.f;
      g_present_mask = 0u;
      g_done = 0u;
    }
    g_part[threadIdx.x][0] = 0.f;
  }
}

extern "C" void kernel_launch(void* const* d_in, const int* in_sizes, int n_in,
                              void* d_out, int out_size, void* d_ws, size_t ws_size,
                              hipStream_t stream) {
  const float* slices = (const float*)d_in[0];
  const int* targets = (const int*)d_in[1];
  float* out = (float*)d_out;
  (void)d_ws; (void)ws_size; (void)in_sizes; (void)n_in; (void)out_size;

  hipLaunchKernelGGL(k_pixel, dim3(NPIX / 2048), dim3(256), 0, stream, slices, targets);
  hipLaunchKernelGGL(k_hscan, dim3(NPLANE * 8), dim3(512), 0, stream);
  hipLaunchKernelGGL(k_wscan, dim3(NPLANE * 32), dim3(256), 0, stream, slices, out);
}

// Round 17
// 168.508 us; speedup vs baseline: 1.2713x; 1.2713x over previous
//
#include <hip/hip_runtime.h>

#define NN 8
#define CC 19
#define HH 512
#define WW 512
#define HW (HH*WW)            // 262144
#define NPIX (NN*HW)          // 2097152
#define NPLANE (NN*CC)        // 152
#define BIGV (1<<20)
#define M7 0x7F7F7F7Fu

// persistent scratch in device globals (zero-initialized at module load;
// k_final restores the zero-state after each use -> replay-invariant)
__device__ unsigned char g_tT[NPIX];                  // targets transposed [n][w][h]
__device__ unsigned char g_pred[NPIX];                // row-major [n][h][w]
__device__ float g_lse[NPIX];                         // row-major
__device__ unsigned char g_inter[(size_t)NPLANE*HW];  // blocked [plane][wt:8][h:512][wl:64]
__device__ float g_ce;
__device__ float g_part[64][16];                      // padded border partials
__device__ float g_dead[64][16];                      // probe sink (never read)
__device__ unsigned int g_present_mask;

// bytewise x==0 -> 0x80 flag (exact, no cross-byte carry)
__device__ __forceinline__ unsigned int eqz(unsigned int x) {
  unsigned int y = (x & M7) + M7;
  return ~(y | x | M7);
}

// per-pixel softmax stats, 8 px/thread, channel-major (R13-verbatim)
__global__ __launch_bounds__(256) void k_pixel(const float* __restrict__ slices,
                                               const int* __restrict__ targets) {
  int bp = blockIdx.x * 2048;                   // block tile: 2048 consecutive px
  int n = bp >> 18;                             // HW = 2^18, 128 blocks/image
  int r = bp & (HW - 1);
  int wv = threadIdx.x >> 6;
  int lane = threadIdx.x & 63;
  int o0 = wv * 512 + lane * 4;
  int o1 = o0 + 256;
  const float* base = slices + (size_t)n * CC * HW + r;

  const int4* t4p = (const int4*)(targets + bp);
  int4 ta = t4p[o0 >> 2];
  int4 tb = t4p[o1 >> 2];
  int t[8] = {ta.x, ta.y, ta.z, ta.w, tb.x, tb.y, tb.z, tb.w};

  float m[8], s[8], pk[8];
  int a[8];
  {
    float4 x0 = *(const float4*)(base + o0);
    float4 x1 = *(const float4*)(base + o1);
    float x[8] = {x0.x, x0.y, x0.z, x0.w, x1.x, x1.y, x1.z, x1.w};
#pragma unroll
    for (int j = 0; j < 8; ++j) {
      m[j] = x[j];
      a[j] = 0;
      s[j] = __expf(x[j]);
      pk[j] = (t[j] == 0) ? x[j] : 0.f;
    }
  }
#pragma unroll 2
  for (int c = 1; c < CC; ++c) {
    float4 x0 = *(const float4*)(base + (size_t)c * HW + o0);
    float4 x1 = *(const float4*)(base + (size_t)c * HW + o1);
    float x[8] = {x0.x, x0.y, x0.z, x0.w, x1.x, x1.y, x1.z, x1.w};
#pragma unroll
    for (int j = 0; j < 8; ++j) {
      if (x[j] > m[j]) { m[j] = x[j]; a[j] = c; }
      s[j] += __expf(x[j]);
      pk[j] = (c == t[j]) ? x[j] : pk[j];
    }
  }

  float l[8];
  float ce_local = 0.f;
  unsigned int msk = 0u;
#pragma unroll
  for (int j = 0; j < 8; ++j) {
    l[j] = __logf(s[j]);
    if (t[j] != 255) ce_local += l[j] - pk[j];
    if ((unsigned)t[j] < CC) msk |= 1u << t[j];
  }

  ((float4*)(g_lse + bp))[o0 >> 2] = make_float4(l[0], l[1], l[2], l[3]);
  ((float4*)(g_lse + bp))[o1 >> 2] = make_float4(l[4], l[5], l[6], l[7]);
  ((uchar4*)(g_pred + bp))[o0 >> 2] =
      make_uchar4((unsigned char)a[0], (unsigned char)a[1],
                  (unsigned char)a[2], (unsigned char)a[3]);
  ((uchar4*)(g_pred + bp))[o1 >> 2] =
      make_uchar4((unsigned char)a[4], (unsigned char)a[5],
                  (unsigned char)a[6], (unsigned char)a[7]);
#pragma unroll
  for (int j = 0; j < 8; ++j) {
    int p = bp + ((j < 4) ? (o0 + j) : (o1 + j - 4));
    int h = (p >> 9) & 511;
    int w = p & 511;
    g_tT[((size_t)n << 18) + (size_t)w * HH + h] = (unsigned char)t[j];
  }

  __shared__ float sred[256];
  __shared__ unsigned int smsk[256];
  sred[threadIdx.x] = ce_local;
  smsk[threadIdx.x] = msk;
  __syncthreads();
  for (int st = 128; st > 0; st >>= 1) {
    if (threadIdx.x < st) {
      sred[threadIdx.x] += sred[threadIdx.x + st];
      smsk[threadIdx.x] |= smsk[threadIdx.x + st];
    }
    __syncthreads();
  }
  if (threadIdx.x == 0) {
    atomicAdd(&g_ce, sred[0]);
    atomicOr(&g_present_mask, smsk[0]);
  }
}

// H-axis scan (R7-verbatim)
__global__ __launch_bounds__(512, 4) void k_hscan() {
  int plane = blockIdx.x >> 3;          // 152 planes
  int wt = blockIdx.x & 7;
  int hc = threadIdx.x >> 6;            // 8 h-chunks of 64
  int wl = threadIdx.x & 63;
  int c = plane % CC;
  int n = plane / CC;
  int w = wt * 64 + wl;
  const unsigned char* colC = g_tT + ((size_t)n << 18) + (size_t)w * HH + hc * 64;

  uint4 ca = *(const uint4*)(colC);
  uint4 cb = *(const uint4*)(colC + 16);
  uint4 cc2 = *(const uint4*)(colC + 32);
  uint4 cd = *(const uint4*)(colC + 48);
  unsigned int cw[16];
  cw[0]=ca.x; cw[1]=ca.y; cw[2]=ca.z; cw[3]=ca.w;
  cw[4]=cb.x; cw[5]=cb.y; cw[6]=cb.z; cw[7]=cb.w;
  cw[8]=cc2.x; cw[9]=cc2.y; cw[10]=cc2.z; cw[11]=cc2.w;
  cw[12]=cd.x; cw[13]=cd.y; cw[14]=cd.z; cw[15]=cd.w;

  unsigned int lw[16];
#pragma unroll
  for (int i = 0; i < 16; ++i) lw[i] = __shfl_up(cw[i], 1, 64);
  if (wl == 0) {
    if (w > 0) {
      const unsigned char* colL = colC - HH;
      uint4 la = *(const uint4*)(colL);
      uint4 lb = *(const uint4*)(colL + 16);
      uint4 lc = *(const uint4*)(colL + 32);
      uint4 ld = *(const uint4*)(colL + 48);
      lw[0]=la.x; lw[1]=la.y; lw[2]=la.z; lw[3]=la.w;
      lw[4]=lb.x; lw[5]=lb.y; lw[6]=lb.z; lw[7]=lb.w;
      lw[8]=lc.x; lw[9]=lc.y; lw[10]=lc.z; lw[11]=lc.w;
      lw[12]=ld.x; lw[13]=ld.y; lw[14]=ld.z; lw[15]=ld.w;
    } else {
#pragma unroll
      for (int i = 0; i < 16; ++i) lw[i] = cw[i];
    }
  }

  __shared__ unsigned char s_edge[8][64];
  s_edge[hc][wl] = (unsigned char)(cw[0] & 255u);
  __syncthreads();
  unsigned int tnl = (hc < 7) ? (unsigned int)s_edge[hc + 1][wl]
                              : ((cw[15] >> 24) & 255u);

  unsigned int bc = (unsigned int)c * 0x01010101u;
  int v[64];
  int prev = BIGV;
#pragma unroll
  for (int i = 0; i < 16; ++i) {
    unsigned int cwi = cw[i];
    unsigned int nxt = (i < 15) ? (cw[i + 1] & 255u) : tnl;
    unsigned int tnw = (cwi >> 8) | (nxt << 24);
    unsigned int zc = eqz(cwi ^ bc);
    unsigned int zn = eqz(tnw ^ bc);
    unsigned int zl = eqz(lw[i] ^ bc);
    unsigned int bb = (zc ^ zn) | (zc ^ zl);
#pragma unroll
    for (int k = 0; k < 4; ++k) {
      int bit = (int)((bb >> (8 * k + 7)) & 1u);
      prev = min(bit ? 0 : 255, prev + 1);
      v[4 * i + k] = prev;
    }
  }

  __shared__ int s_car[8][64];
  s_car[hc][wl] = v[63];
  __syncthreads();
  int F = BIGV;
#pragma unroll
  for (int i = 0; i < 7; ++i)
    if (i < hc) F = min(s_car[i][wl] + 1, F + 64);
#pragma unroll
  for (int k = 0; k < 64; ++k) v[k] = min(v[k], F + k);

#pragma unroll
  for (int k = 62; k >= 0; --k) v[k] = min(v[k], v[k + 1] + 1);

  __syncthreads();
  s_car[hc][wl] = v[0];
  __syncthreads();
  int B = BIGV;
#pragma unroll
  for (int j = 7; j >= 1; --j)
    if (j > hc) B = min(s_car[j][wl] + 1, B + 64);

  unsigned char* outb = g_inter + (((size_t)plane * 8 + wt) * HH + hc * 64) * 64 + wl;
#pragma unroll
  for (int k = 0; k < 64; ++k) {
    int outv = min(v[k], B + (63 - k));
    outb[(size_t)k * 64] = (unsigned char)outv;
  }
}

// W-axis scan + fused sparse accumulation (R13-verbatim, the real one)
__global__ __launch_bounds__(512) void k_wscan(const float* __restrict__ slices) {
  int plane = blockIdx.x >> 6;          // 152 planes
  int hg = blockIdx.x & 63;             // 64 h-groups of 8 rows
  int wv = threadIdx.x >> 6;            // 8 waves
  int lane = threadIdx.x & 63;
  int h = hg * 8 + wv;
  int c = plane % CC;
  int n = plane / CC;

  const unsigned char* rowp =
      g_inter + (((size_t)plane * 8 + (lane >> 3)) * HH + h) * 64 + (lane & 7) * 8;
  uint2 r8 = *(const uint2*)rowp;

  int d0[8];
#pragma unroll
  for (int k = 0; k < 4; ++k) {
    d0[k]     = (int)((r8.x >> (k * 8)) & 255u);
    d0[k + 4] = (int)((r8.y >> (k * 8)) & 255u);
  }
  int ls[8];
  ls[0] = d0[0];
#pragma unroll
  for (int k = 1; k < 8; ++k) ls[k] = min(d0[k], ls[k - 1] + 1);
  int u = ls[7] - 8 * lane;
#pragma unroll
  for (int o = 1; o < 64; o <<= 1) {
    int t = __shfl_up(u, o, 64);
    if (lane >= o) u = min(u, t);
  }
  int cf = __shfl_up(u, 1, 64);
  int carry = (lane == 0) ? BIGV : cf + 8 * (lane - 1);
  int f[8];
#pragma unroll
  for (int k = 0; k < 8; ++k) f[k] = min(ls[k], carry + k + 1);
  int bs[8];
  bs[7] = f[7];
#pragma unroll
  for (int k = 6; k >= 0; --k) bs[k] = min(f[k], bs[k + 1] + 1);
  int mm = bs[0] + 8 * lane;
#pragma unroll
  for (int o = 1; o < 64; o <<= 1) {
    int t = __shfl_down(mm, o, 64);
    if (lane + o < 64) mm = min(mm, t);
  }
  int mb = __shfl_down(mm, 1, 64);
  int carryb = (lane == 63) ? BIGV : mb - 8 * lane;

  float acc = 0.f;
#pragma unroll
  for (int k = 0; k < 8; ++k) {
    int D = min(bs[k], carryb - k);
    int d = D - 5;                        // BORDER_DILATE
    if (d > 0) {
      int w = lane * 8 + k;
      int pix = (n * HH + h) * WW + w;
      int pcv = g_pred[pix];
      int pnv = (h + 1 < HH) ? g_pred[pix + WW] : pcv;
      int plv = (w > 0) ? g_pred[pix - 1] : pcv;
      bool ec = (pcv == c);
      if ((ec != (pnv == c)) || (ec != (plv == c))) {
        float x = slices[((size_t)n * CC + c) * HW + (size_t)h * WW + w];
        float smv = __expf(x - g_lse[pix]);
        acc += smv * (float)d;
      }
    }
  }

#pragma unroll
  for (int o = 32; o > 0; o >>= 1) acc += __shfl_down(acc, o, 64);
  if (lane == 0) {
    float pres = (g_present_mask >> c) & 1u ? 1.f : 0.f;
    atomicAdd(&g_part[blockIdx.x & 63][0], acc * pres);
  }
}

// PROBE: identical load + shuffle-scan, sparse-accum replaced by acc += D.
// x2 internal reps (pointer laundered so the scan re-executes). Sinks to
// g_dead (never read). Measures the load+scan half of wscan's cost.
__global__ __launch_bounds__(512) void k_probe(float* __restrict__ sink) {
  int plane = blockIdx.x >> 6;
  int hg = blockIdx.x & 63;
  int wv = threadIdx.x >> 6;
  int lane = threadIdx.x & 63;
  int h = hg * 8 + wv;

  const unsigned char* rowp =
      g_inter + (((size_t)plane * 8 + (lane >> 3)) * HH + h) * 64 + (lane & 7) * 8;
  float acc = 0.f;
#pragma unroll 1
  for (int rep = 0; rep < 2; ++rep) {
    const unsigned char* rp = rowp;
    asm volatile("" : "+v"(rp));          // launder: force re-load + re-scan
    uint2 r8 = *(const uint2*)rp;

    int d0[8];
#pragma unroll
    for (int k = 0; k < 4; ++k) {
      d0[k]     = (int)((r8.x >> (k * 8)) & 255u);
      d0[k + 4] = (int)((r8.y >> (k * 8)) & 255u);
    }
    int ls[8];
    ls[0] = d0[0];
#pragma unroll
    for (int k = 1; k < 8; ++k) ls[k] = min(d0[k], ls[k - 1] + 1);
    int u = ls[7] - 8 * lane;
#pragma unroll
    for (int o = 1; o < 64; o <<= 1) {
      int t = __shfl_up(u, o, 64);
      if (lane >= o) u = min(u, t);
    }
    int cf = __shfl_up(u, 1, 64);
    int carry = (lane == 0) ? BIGV : cf + 8 * (lane - 1);
    int f[8];
#pragma unroll
    for (int k = 0; k < 8; ++k) f[k] = min(ls[k], carry + k + 1);
    int bs[8];
    bs[7] = f[7];
#pragma unroll
    for (int k = 6; k >= 0; --k) bs[k] = min(f[k], bs[k + 1] + 1);
    int mm = bs[0] + 8 * lane;
#pragma unroll
    for (int o = 1; o < 64; o <<= 1) {
      int t = __shfl_down(mm, o, 64);
      if (lane + o < 64) mm = min(mm, t);
    }
    int mb = __shfl_down(mm, 1, 64);
    int carryb = (lane == 63) ? BIGV : mb - 8 * lane;

#pragma unroll
    for (int k = 0; k < 8; ++k) {
      int D = min(bs[k], carryb - k);
      acc += (float)D;                    // keep scan live; no sparse path
    }
  }

#pragma unroll
  for (int o = 32; o > 0; o >>= 1) acc += __shfl_down(acc, o, 64);
  if (lane == 0) atomicAdd(&sink[(blockIdx.x & 63) * 16], acc);
}

// final sum (one wave) + output; resets state for replay determinism
__global__ void k_final(float* __restrict__ out) {
  int t = threadIdx.x;
  float b = g_part[t][0];
#pragma unroll
  for (int o = 32; o > 0; o >>= 1) b += __shfl_down(b, o, 64);
  if (t == 0) {
    out[0] = g_ce + sqrtf(b);             // BORDER_WEIGHT=1, power=0.5
    g_ce = 0.f;
    g_present_mask = 0u;
  }
  g_part[t][0] = 0.f;
}

extern "C" void kernel_launch(void* const* d_in, const int* in_sizes, int n_in,
                              void* d_out, int out_size, void* d_ws, size_t ws_size,
                              hipStream_t stream) {
  const float* slices = (const float*)d_in[0];
  const int* targets = (const int*)d_in[1];
  float* out = (float*)d_out;
  (void)d_ws; (void)ws_size; (void)in_sizes; (void)n_in; (void)out_size;

  float* dead;
  hipGetSymbolAddress((void**)&dead, HIP_SYMBOL(g_dead));

  hipLaunchKernelGGL(k_pixel, dim3(NPIX / 2048), dim3(256), 0, stream, slices, targets);
  hipLaunchKernelGGL(k_hscan, dim3(NPLANE * 8), dim3(512), 0, stream);
  hipLaunchKernelGGL(k_wscan, dim3(NPLANE * 64), dim3(512), 0, stream, slices);
  hipLaunchKernelGGL(k_probe, dim3(NPLANE * 64), dim3(512), 0, stream, dead);
  hipLaunchKernelGGL(k_final, dim3(1), dim3(64), 0, stream, out);
}

// Round 18
// 117.891 us; speedup vs baseline: 1.8171x; 1.4293x over previous
//
#include <hip/hip_runtime.h>

#define NN 8
#define CC 19
#define HH 512
#define WW 512
#define HW (HH*WW)            // 262144
#define NPIX (NN*HW)          // 2097152
#define NPLANE (NN*CC)        // 152
#define BIGV (1<<20)
#define M7 0x7F7F7F7Fu

// persistent scratch in device globals (zero-initialized at module load;
// k_final restores the zero-state after each use -> replay-invariant)
__device__ unsigned char g_tT[NPIX];                  // targets transposed [n][w][h]
__device__ unsigned char g_pred[NPIX];                // row-major [n][h][w]
__device__ float g_lse[NPIX];                         // row-major
__device__ unsigned char g_inter[(size_t)NPLANE*HW];  // blocked [plane][wt:8][h:512][wl:64]
__device__ unsigned char g_pbb[(size_t)NPLANE*HW/8];  // pred-boundary bits, same blocked geom
__device__ float g_ce;
__device__ float g_part[64][16];                      // padded border partials
__device__ unsigned int g_present_mask;

// bytewise x==0 -> 0x80 flag (exact, no cross-byte carry)
__device__ __forceinline__ unsigned int eqz(unsigned int x) {
  unsigned int y = (x & M7) + M7;
  return ~(y | x | M7);
}

// per-pixel softmax stats, 8 px/thread, channel-major (R13-verbatim)
__global__ __launch_bounds__(256) void k_pixel(const float* __restrict__ slices,
                                               const int* __restrict__ targets) {
  int bp = blockIdx.x * 2048;                   // block tile: 2048 consecutive px
  int n = bp >> 18;                             // HW = 2^18, 128 blocks/image
  int r = bp & (HW - 1);
  int wv = threadIdx.x >> 6;
  int lane = threadIdx.x & 63;
  int o0 = wv * 512 + lane * 4;
  int o1 = o0 + 256;
  const float* base = slices + (size_t)n * CC * HW + r;

  const int4* t4p = (const int4*)(targets + bp);
  int4 ta = t4p[o0 >> 2];
  int4 tb = t4p[o1 >> 2];
  int t[8] = {ta.x, ta.y, ta.z, ta.w, tb.x, tb.y, tb.z, tb.w};

  float m[8], s[8], pk[8];
  int a[8];
  {
    float4 x0 = *(const float4*)(base + o0);
    float4 x1 = *(const float4*)(base + o1);
    float x[8] = {x0.x, x0.y, x0.z, x0.w, x1.x, x1.y, x1.z, x1.w};
#pragma unroll
    for (int j = 0; j < 8; ++j) {
      m[j] = x[j];
      a[j] = 0;
      s[j] = __expf(x[j]);
      pk[j] = (t[j] == 0) ? x[j] : 0.f;
    }
  }
#pragma unroll 2
  for (int c = 1; c < CC; ++c) {
    float4 x0 = *(const float4*)(base + (size_t)c * HW + o0);
    float4 x1 = *(const float4*)(base + (size_t)c * HW + o1);
    float x[8] = {x0.x, x0.y, x0.z, x0.w, x1.x, x1.y, x1.z, x1.w};
#pragma unroll
    for (int j = 0; j < 8; ++j) {
      if (x[j] > m[j]) { m[j] = x[j]; a[j] = c; }
      s[j] += __expf(x[j]);
      pk[j] = (c == t[j]) ? x[j] : pk[j];
    }
  }

  float l[8];
  float ce_local = 0.f;
  unsigned int msk = 0u;
#pragma unroll
  for (int j = 0; j < 8; ++j) {
    l[j] = __logf(s[j]);
    if (t[j] != 255) ce_local += l[j] - pk[j];
    if ((unsigned)t[j] < CC) msk |= 1u << t[j];
  }

  ((float4*)(g_lse + bp))[o0 >> 2] = make_float4(l[0], l[1], l[2], l[3]);
  ((float4*)(g_lse + bp))[o1 >> 2] = make_float4(l[4], l[5], l[6], l[7]);
  ((uchar4*)(g_pred + bp))[o0 >> 2] =
      make_uchar4((unsigned char)a[0], (unsigned char)a[1],
                  (unsigned char)a[2], (unsigned char)a[3]);
  ((uchar4*)(g_pred + bp))[o1 >> 2] =
      make_uchar4((unsigned char)a[4], (unsigned char)a[5],
                  (unsigned char)a[6], (unsigned char)a[7]);
#pragma unroll
  for (int j = 0; j < 8; ++j) {
    int p = bp + ((j < 4) ? (o0 + j) : (o1 + j - 4));
    int h = (p >> 9) & 511;
    int w = p & 511;
    g_tT[((size_t)n << 18) + (size_t)w * HH + h] = (unsigned char)t[j];
  }

  __shared__ float sred[256];
  __shared__ unsigned int smsk[256];
  sred[threadIdx.x] = ce_local;
  smsk[threadIdx.x] = msk;
  __syncthreads();
  for (int st = 128; st > 0; st >>= 1) {
    if (threadIdx.x < st) {
      sred[threadIdx.x] += sred[threadIdx.x + st];
      smsk[threadIdx.x] |= smsk[threadIdx.x + st];
    }
    __syncthreads();
  }
  if (threadIdx.x == 0) {
    atomicAdd(&g_ce, sred[0]);
    atomicOr(&g_present_mask, smsk[0]);
  }
}

// pred-boundary bit generator: g_pbb[plane][wt][h][j] bit k = "pixel
// (n, h, wt*64+j*8+k) is a pred-boundary for class c = plane%CC".
// Pure streaming: 2x64B pred reads + 8B write per thread.
__global__ __launch_bounds__(512) void k_pbb() {
  int plane = blockIdx.x >> 3;          // 152 planes
  int wt = blockIdx.x & 7;
  int c = plane % CC;
  int n = plane / CC;
  int h = threadIdx.x;                  // 512 rows

  const unsigned char* row = g_pred + ((size_t)n * HH + h) * WW + wt * 64;
  const unsigned char* rown = (h + 1 < HH) ? row + WW : row;   // tb pad: en=ec

  uint4 c0 = *(const uint4*)(row);
  uint4 c1 = *(const uint4*)(row + 16);
  uint4 c2 = *(const uint4*)(row + 32);
  uint4 c3 = *(const uint4*)(row + 48);
  uint4 n0 = *(const uint4*)(rown);
  uint4 n1 = *(const uint4*)(rown + 16);
  uint4 n2 = *(const uint4*)(rown + 32);
  uint4 n3 = *(const uint4*)(rown + 48);
  unsigned int cwv[16] = {c0.x,c0.y,c0.z,c0.w, c1.x,c1.y,c1.z,c1.w,
                          c2.x,c2.y,c2.z,c2.w, c3.x,c3.y,c3.z,c3.w};
  unsigned int nwv[16] = {n0.x,n0.y,n0.z,n0.w, n1.x,n1.y,n1.z,n1.w,
                          n2.x,n2.y,n2.z,n2.w, n3.x,n3.y,n3.z,n3.w};
  int leftb = (wt > 0) ? (int)row[-1] : (int)(cwv[0] & 255u);  // w=0: el=ec

  unsigned char outb[8];
  int pl = leftb;
#pragma unroll
  for (int j = 0; j < 8; ++j) {
    unsigned int bits = 0u;
#pragma unroll
    for (int k = 0; k < 8; ++k) {
      int q = j * 8 + k;
      int pc = (int)((cwv[q >> 2] >> ((q & 3) * 8)) & 255u);
      int pn = (int)((nwv[q >> 2] >> ((q & 3) * 8)) & 255u);
      bool ec = (pc == c);
      bool bb = (ec != (pn == c)) || (ec != (pl == c));
      bits |= (bb ? 1u : 0u) << k;
      pl = pc;
    }
    outb[j] = (unsigned char)bits;
  }
  unsigned char* dst = g_pbb + (((size_t)plane * 8 + wt) * HH + h) * 8;
  *(uint2*)dst = *(const uint2*)outb;
}

// H-axis scan (R7-verbatim)
__global__ __launch_bounds__(512, 4) void k_hscan() {
  int plane = blockIdx.x >> 3;          // 152 planes
  int wt = blockIdx.x & 7;
  int hc = threadIdx.x >> 6;            // 8 h-chunks of 64
  int wl = threadIdx.x & 63;
  int c = plane % CC;
  int n = plane / CC;
  int w = wt * 64 + wl;
  const unsigned char* colC = g_tT + ((size_t)n << 18) + (size_t)w * HH + hc * 64;

  uint4 ca = *(const uint4*)(colC);
  uint4 cb = *(const uint4*)(colC + 16);
  uint4 cc2 = *(const uint4*)(colC + 32);
  uint4 cd = *(const uint4*)(colC + 48);
  unsigned int cw[16];
  cw[0]=ca.x; cw[1]=ca.y; cw[2]=ca.z; cw[3]=ca.w;
  cw[4]=cb.x; cw[5]=cb.y; cw[6]=cb.z; cw[7]=cb.w;
  cw[8]=cc2.x; cw[9]=cc2.y; cw[10]=cc2.z; cw[11]=cc2.w;
  cw[12]=cd.x; cw[13]=cd.y; cw[14]=cd.z; cw[15]=cd.w;

  unsigned int lw[16];
#pragma unroll
  for (int i = 0; i < 16; ++i) lw[i] = __shfl_up(cw[i], 1, 64);
  if (wl == 0) {
    if (w > 0) {
      const unsigned char* colL = colC - HH;
      uint4 la = *(const uint4*)(colL);
      uint4 lb = *(const uint4*)(colL + 16);
      uint4 lc = *(const uint4*)(colL + 32);
      uint4 ld = *(const uint4*)(colL + 48);
      lw[0]=la.x; lw[1]=la.y; lw[2]=la.z; lw[3]=la.w;
      lw[4]=lb.x; lw[5]=lb.y; lw[6]=lb.z; lw[7]=lb.w;
      lw[8]=lc.x; lw[9]=lc.y; lw[10]=lc.z; lw[11]=lc.w;
      lw[12]=ld.x; lw[13]=ld.y; lw[14]=ld.z; lw[15]=ld.w;
    } else {
#pragma unroll
      for (int i = 0; i < 16; ++i) lw[i] = cw[i];
    }
  }

  __shared__ unsigned char s_edge[8][64];
  s_edge[hc][wl] = (unsigned char)(cw[0] & 255u);
  __syncthreads();
  unsigned int tnl = (hc < 7) ? (unsigned int)s_edge[hc + 1][wl]
                              : ((cw[15] >> 24) & 255u);

  unsigned int bc = (unsigned int)c * 0x01010101u;
  int v[64];
  int prev = BIGV;
#pragma unroll
  for (int i = 0; i < 16; ++i) {
    unsigned int cwi = cw[i];
    unsigned int nxt = (i < 15) ? (cw[i + 1] & 255u) : tnl;
    unsigned int tnw = (cwi >> 8) | (nxt << 24);
    unsigned int zc = eqz(cwi ^ bc);
    unsigned int zn = eqz(tnw ^ bc);
    unsigned int zl = eqz(lw[i] ^ bc);
    unsigned int bb = (zc ^ zn) | (zc ^ zl);
#pragma unroll
    for (int k = 0; k < 4; ++k) {
      int bit = (int)((bb >> (8 * k + 7)) & 1u);
      prev = min(bit ? 0 : 255, prev + 1);
      v[4 * i + k] = prev;
    }
  }

  __shared__ int s_car[8][64];
  s_car[hc][wl] = v[63];
  __syncthreads();
  int F = BIGV;
#pragma unroll
  for (int i = 0; i < 7; ++i)
    if (i < hc) F = min(s_car[i][wl] + 1, F + 64);
#pragma unroll
  for (int k = 0; k < 64; ++k) v[k] = min(v[k], F + k);

#pragma unroll
  for (int k = 62; k >= 0; --k) v[k] = min(v[k], v[k + 1] + 1);

  __syncthreads();
  s_car[hc][wl] = v[0];
  __syncthreads();
  int B = BIGV;
#pragma unroll
  for (int j = 7; j >= 1; --j)
    if (j > hc) B = min(s_car[j][wl] + 1, B + 64);

  unsigned char* outb = g_inter + (((size_t)plane * 8 + wt) * HH + hc * 64) * 64 + wl;
#pragma unroll
  for (int k = 0; k < 64; ++k) {
    int outv = min(v[k], B + (63 - k));
    outb[(size_t)k * 64] = (unsigned char)outv;
  }
}

// W-axis scan + sparse accumulation gated by precomputed pred-boundary bits:
// no scattered loads in the hot path (pbb byte loaded unconditionally,
// coalesced with the distance row; slices/lse only at d>0 && bit ~ 0.03%).
__global__ __launch_bounds__(512) void k_wscan(const float* __restrict__ slices) {
  int plane = blockIdx.x >> 6;          // 152 planes
  int hg = blockIdx.x & 63;             // 64 h-groups of 8 rows
  int wv = threadIdx.x >> 6;            // 8 waves
  int lane = threadIdx.x & 63;
  int h = hg * 8 + wv;
  int c = plane % CC;
  int n = plane / CC;

  const unsigned char* rowp =
      g_inter + (((size_t)plane * 8 + (lane >> 3)) * HH + h) * 64 + (lane & 7) * 8;
  uint2 r8 = *(const uint2*)rowp;
  unsigned int pbb = (unsigned int)
      g_pbb[(((size_t)plane * 8 + (lane >> 3)) * HH + h) * 8 + (lane & 7)];

  int d0[8];
#pragma unroll
  for (int k = 0; k < 4; ++k) {
    d0[k]     = (int)((r8.x >> (k * 8)) & 255u);
    d0[k + 4] = (int)((r8.y >> (k * 8)) & 255u);
  }
  int ls[8];
  ls[0] = d0[0];
#pragma unroll
  for (int k = 1; k < 8; ++k) ls[k] = min(d0[k], ls[k - 1] + 1);
  int u = ls[7] - 8 * lane;
#pragma unroll
  for (int o = 1; o < 64; o <<= 1) {
    int t = __shfl_up(u, o, 64);
    if (lane >= o) u = min(u, t);
  }
  int cf = __shfl_up(u, 1, 64);
  int carry = (lane == 0) ? BIGV : cf + 8 * (lane - 1);
  int f[8];
#pragma unroll
  for (int k = 0; k < 8; ++k) f[k] = min(ls[k], carry + k + 1);
  int bs[8];
  bs[7] = f[7];
#pragma unroll
  for (int k = 6; k >= 0; --k) bs[k] = min(f[k], bs[k + 1] + 1);
  int mm = bs[0] + 8 * lane;
#pragma unroll
  for (int o = 1; o < 64; o <<= 1) {
    int t = __shfl_down(mm, o, 64);
    if (lane + o < 64) mm = min(mm, t);
  }
  int mb = __shfl_down(mm, 1, 64);
  int carryb = (lane == 63) ? BIGV : mb - 8 * lane;

  float acc = 0.f;
#pragma unroll
  for (int k = 0; k < 8; ++k) {
    int D = min(bs[k], carryb - k);
    int d = D - 5;                        // BORDER_DILATE
    if (d > 0 && ((pbb >> k) & 1u)) {     // joint density ~0.03%
      int w = lane * 8 + k;
      int pix = (n * HH + h) * WW + w;
      float x = slices[((size_t)n * CC + c) * HW + (size_t)h * WW + w];
      float smv = __expf(x - g_lse[pix]);
      acc += smv * (float)d;
    }
  }

#pragma unroll
  for (int o = 32; o > 0; o >>= 1) acc += __shfl_down(acc, o, 64);
  if (lane == 0) {
    float pres = (g_present_mask >> c) & 1u ? 1.f : 0.f;
    atomicAdd(&g_part[blockIdx.x & 63][0], acc * pres);
  }
}

// final sum (one wave) + output; resets state for replay determinism
__global__ void k_final(float* __restrict__ out) {
  int t = threadIdx.x;
  float b = g_part[t][0];
#pragma unroll
  for (int o = 32; o > 0; o >>= 1) b += __shfl_down(b, o, 64);
  if (t == 0) {
    out[0] = g_ce + sqrtf(b);             // BORDER_WEIGHT=1, power=0.5
    g_ce = 0.f;
    g_present_mask = 0u;
  }
  g_part[t][0] = 0.f;
}

extern "C" void kernel_launch(void* const* d_in, const int* in_sizes, int n_in,
                              void* d_out, int out_size, void* d_ws, size_t ws_size,
                              hipStream_t stream) {
  const float* slices = (const float*)d_in[0];
  const int* targets = (const int*)d_in[1];
  float* out = (float*)d_out;
  (void)d_ws; (void)ws_size; (void)in_sizes; (void)n_in; (void)out_size;

  hipLaunchKernelGGL(k_pixel, dim3(NPIX / 2048), dim3(256), 0, stream, slices, targets);
  hipLaunchKernelGGL(k_pbb, dim3(NPLANE * 8), dim3(512), 0, stream);
  hipLaunchKernelGGL(k_hscan, dim3(NPLANE * 8), dim3(512), 0, stream);
  hipLaunchKernelGGL(k_wscan, dim3(NPLANE * 64), dim3(512), 0, stream, slices);
  hipLaunchKernelGGL(k_final, dim3(1), dim3(64), 0, stream, out);
}